// Round 2
// baseline (1486.618 us; speedup 1.0000x reference)
//
#include <hip/hip_runtime.h>
#include <math.h>

#define BB 2
#define CCH 128
#define HH 192
#define WW 192
#define KK 9
#define HWs (HH*WW)          // 36864
#define NPIX (BB*HWs)        // 73728

__device__ __forceinline__ int iclamp(int v, int lo, int hi) {
    return v < lo ? lo : (v > hi ? hi : v);
}

// ---------------------------------------------------------------------------
// Weight pre-transpose: in (O, C, 3, 3) -> out (9, C, OP) [o<O valid, pad 0]
// ---------------------------------------------------------------------------
__global__ void transpose_w_kernel(const float* __restrict__ in,
                                   float* __restrict__ outp, int O, int OP) {
    int idx = blockIdx.x * 256 + threadIdx.x;
    int total = 9 * CCH * OP;
    if (idx >= total) return;
    int o = idx % OP;
    int c = (idx / OP) % CCH;
    int tap = idx / (OP * CCH);
    outp[idx] = (o < O) ? in[(o * CCH + c) * 9 + tap] : 0.0f;
}

// ---------------------------------------------------------------------------
// NCHW -> NHWC transpose with optional instance-norm + relu
// ---------------------------------------------------------------------------
__global__ __launch_bounds__(256) void transpose_nhwc_kernel(
    const float* __restrict__ in, float* __restrict__ outp,
    const float* __restrict__ mu, const float* __restrict__ rs, int do_relu) {
    __shared__ float tile[32][33];
    int blk = blockIdx.x;                 // ((b*H + y)*6 + xt)*4 + ct
    int ct = blk & 3;
    int rest = blk >> 2;
    int xt = rest % 6;
    int rest2 = rest / 6;
    int y = rest2 % HH;
    int b = rest2 / HH;
    int i = threadIdx.x & 31;
    int j = threadIdx.x >> 5;             // 0..7
#pragma unroll
    for (int r = 0; r < 4; ++r) {
        int cl = j + r * 8;
        int c = ct * 32 + cl;
        float v = in[((size_t)(b * CCH + c) * HH + y) * WW + xt * 32 + i];
        if (mu != nullptr) v = (v - mu[b * CCH + c]) * rs[b * CCH + c];
        if (do_relu) v = fmaxf(v, 0.0f);
        tile[cl][i] = v;
    }
    __syncthreads();
#pragma unroll
    for (int r = 0; r < 4; ++r) {
        int xl = j + r * 8;
        outp[(((size_t)b * HH + y) * WW + xt * 32 + xl) * CCH + ct * 32 + i] =
            tile[i][xl];
    }
}

// ---------------------------------------------------------------------------
// Offset/mask conv (27 out channels, 3x3, pad 1) fused with sampling-record
// generation. One thread per pixel. samp record per (pixel,k): 4 flat spatial
// indices (int-as-float) + 4 bilinear weights (validity & mask folded).
// ---------------------------------------------------------------------------
__global__ __launch_bounds__(256) void om_conv_kernel(
    const float* __restrict__ lo,    // (B,C,H,W)
    const float* __restrict__ wT,    // (9, C, 28) padded
    const float* __restrict__ bom,   // (27)
    float* __restrict__ samp) {      // (B,H,W,9,8)
    int pix = blockIdx.x * 256 + threadIdx.x;   // exactly 73728
    int b = pix / HWs;
    int rem = pix % HWs;
    int y = rem / WW;
    int x = rem % WW;
    float acc[27];
#pragma unroll
    for (int o = 0; o < 27; ++o) acc[o] = bom[o];
    const float* lob = lo + (size_t)b * CCH * HWs;
#pragma unroll
    for (int tap = 0; tap < 9; ++tap) {
        int ty = tap / 3 - 1, tx = tap % 3 - 1;
        int yy = y + ty, xx = x + tx;
        bool ok = (yy >= 0 && yy < HH && xx >= 0 && xx < WW);
        int yyc = iclamp(yy, 0, HH - 1), xxc = iclamp(xx, 0, WW - 1);
        const float* lp = lob + yyc * WW + xxc;
        const float* wp = wT + tap * CCH * 28;
#pragma unroll 2
        for (int c = 0; c < CCH; ++c) {
            float v = lp[(size_t)c * HWs];
            v = ok ? v : 0.0f;
            const float* wpc = wp + c * 28;
#pragma unroll
            for (int o = 0; o < 27; ++o) acc[o] = fmaf(v, wpc[o], acc[o]);
        }
    }
    size_t sbase = (size_t)pix * 72;
#pragma unroll
    for (int k = 0; k < 9; ++k) {
        float dy = acc[2 * k], dx = acc[2 * k + 1];
        float m = 1.0f / (1.0f + __expf(-acc[18 + k]));
        float py = (float)y + (float)(k / 3 - 1) + dy;
        float px = (float)x + (float)(k % 3 - 1) + dx;
        py = fminf(fmaxf(py, -2.0f), (float)(HH + 1));
        px = fminf(fmaxf(px, -2.0f), (float)(WW + 1));
        float y0f = floorf(py), x0f = floorf(px);
        float ay = py - y0f, ax = px - x0f;
        int y0 = (int)y0f, x0 = (int)x0f;
        int y1 = y0 + 1, x1 = x0 + 1;
        bool vy0 = (y0 >= 0 && y0 < HH), vy1 = (y1 >= 0 && y1 < HH);
        bool vx0 = (x0 >= 0 && x0 < WW), vx1 = (x1 >= 0 && x1 < WW);
        int y0c = iclamp(y0, 0, HH - 1), y1c = iclamp(y1, 0, HH - 1);
        int x0c = iclamp(x0, 0, WW - 1), x1c = iclamp(x1, 0, WW - 1);
        float w00 = (1.0f - ay) * (1.0f - ax) * ((vy0 && vx0) ? m : 0.0f);
        float w01 = (1.0f - ay) * ax * ((vy0 && vx1) ? m : 0.0f);
        float w10 = ay * (1.0f - ax) * ((vy1 && vx0) ? m : 0.0f);
        float w11 = ay * ax * ((vy1 && vx1) ? m : 0.0f);
        float4 s0, s1;
        s0.x = __int_as_float(y0c * WW + x0c);
        s0.y = __int_as_float(y0c * WW + x1c);
        s0.z = __int_as_float(y1c * WW + x0c);
        s0.w = __int_as_float(y1c * WW + x1c);
        s1.x = w00; s1.y = w01; s1.z = w10; s1.w = w11;
        *(float4*)(samp + sbase + (size_t)k * 8) = s0;
        *(float4*)(samp + sbase + (size_t)k * 8 + 4) = s1;
    }
}

// ---------------------------------------------------------------------------
// DCN: gather + per-pixel GEMM. Block = 64 pixels (one row segment) x 128 out.
// Per k: stage S[c][p] (LDS, stride 68) via bilinear gathers from NHWC input,
// then register-tiled 8o x 4p FMA loop over c with W (k,c,o) from L2.
// LDS bank audit: b128 writes at word-stride 68 hit all 32 banks exactly 8x
// per wave (the 64-lane b128 floor) - optimal. Compute reads: 16 distinct
// addrs, 2 phases + broadcast - optimal. No swizzle needed.
// ---------------------------------------------------------------------------
#define DP 64
__global__ __launch_bounds__(256) void dcn_kernel(
    const float* __restrict__ xh,    // (B,H,W,C) NHWC
    const float* __restrict__ samp,  // (B,H,W,9,8)
    const float* __restrict__ Wt,    // (9, C, O) = [k][c][o]
    const float* __restrict__ bias,  // (128)
    float* __restrict__ outp) {      // (B,C,H,W)
    __shared__ float s_samp[DP * 72];   // 18 KB
    __shared__ float s_S[128 * 68];     // 34.8 KB
    int blk = blockIdx.x;               // 1152
    int xt = blk % (WW / DP);
    int y = (blk / (WW / DP)) % HH;
    int b = blk / ((WW / DP) * HH);
    int x0 = xt * DP;
    int t = threadIdx.x;

    // stage the block's sampling records (contiguous 4608 floats)
    const float* sg = samp + ((size_t)(b * HH + y) * WW + x0) * 72;
    for (int i = t; i < DP * 72 / 4; i += 256)
        *(float4*)&s_samp[i * 4] = *(const float4*)&sg[(size_t)i * 4];

    int oi = t >> 4;          // 0..15  -> o = oi*8
    int pi = t & 15;          // 0..15  -> p = pi*4
    int o = oi * 8;
    float acc[8][4];
#pragma unroll
    for (int io = 0; io < 8; ++io)
#pragma unroll
        for (int j = 0; j < 4; ++j) acc[io][j] = 0.0f;

    int cc = t & 127;         // staging channel
    int pg = t >> 7;          // 0/1
    const float* xb = xh + (size_t)b * HWs * CCH;

    for (int k = 0; k < KK; ++k) {
        __syncthreads();      // prev-iter reads of s_S done (also covers s_samp)
        // ---- stage S for this k ----
        for (int i = 0; i < 8; ++i) {
            int pbase = pg * 32 + i * 4;
            float4 sv;
#pragma unroll
            for (int j = 0; j < 4; ++j) {
                const float* sd = &s_samp[(pbase + j) * 72 + k * 8];
                int i00 = __float_as_int(sd[0]);
                int i01 = __float_as_int(sd[1]);
                int i10 = __float_as_int(sd[2]);
                int i11 = __float_as_int(sd[3]);
                float v = sd[4] * xb[(size_t)i00 * CCH + cc] +
                          sd[5] * xb[(size_t)i01 * CCH + cc] +
                          sd[6] * xb[(size_t)i10 * CCH + cc] +
                          sd[7] * xb[(size_t)i11 * CCH + cc];
                ((float*)&sv)[j] = v;
            }
            *(float4*)&s_S[cc * 68 + pbase] = sv;
        }
        __syncthreads();
        // ---- compute ----
        const float* wk = Wt + (size_t)k * CCH * CCH;
#pragma unroll 2
        for (int c = 0; c < CCH; ++c) {
            const float4 s4 = *(const float4*)&s_S[c * 68 + (pi << 2)];
            const float4 wa = *(const float4*)&wk[c * CCH + o];
            const float4 wb = *(const float4*)&wk[c * CCH + o + 4];
            float ss[4] = {s4.x, s4.y, s4.z, s4.w};
            float ws8[8] = {wa.x, wa.y, wa.z, wa.w, wb.x, wb.y, wb.z, wb.w};
#pragma unroll
            for (int io = 0; io < 8; ++io)
#pragma unroll
                for (int j = 0; j < 4; ++j)
                    acc[io][j] = fmaf(ws8[io], ss[j], acc[io][j]);
        }
    }
    // ---- epilogue ----
#pragma unroll
    for (int io = 0; io < 8; ++io) {
        float bo = bias[o + io];
        float4 r;
        r.x = acc[io][0] + bo;
        r.y = acc[io][1] + bo;
        r.z = acc[io][2] + bo;
        r.w = acc[io][3] + bo;
        *(float4*)&outp[((size_t)(b * CCH + o + io) * HH + y) * WW + x0 +
                        (pi << 2)] = r;
    }
}

// ---------------------------------------------------------------------------
// Per-(b,c) mean / rsqrt(var+eps)
// ---------------------------------------------------------------------------
__global__ __launch_bounds__(256) void stats_kernel(
    const float* __restrict__ d, float* __restrict__ mu,
    float* __restrict__ rs) {
    int ch = blockIdx.x;   // 256
    const float* p = d + (size_t)ch * HWs;
    float s = 0.0f, s2 = 0.0f;
    for (int i = threadIdx.x; i < HWs / 4; i += 256) {
        float4 v = *(const float4*)&p[(size_t)i * 4];
        s += v.x + v.y + v.z + v.w;
        s2 += v.x * v.x + v.y * v.y + v.z * v.z + v.w * v.w;
    }
#pragma unroll
    for (int off = 32; off > 0; off >>= 1) {
        s += __shfl_down(s, off);
        s2 += __shfl_down(s2, off);
    }
    __shared__ float red[8];
    int wid = threadIdx.x >> 6;
    if ((threadIdx.x & 63) == 0) { red[wid] = s; red[4 + wid] = s2; }
    __syncthreads();
    if (threadIdx.x == 0) {
        s = red[0] + red[1] + red[2] + red[3];
        s2 = red[4] + red[5] + red[6] + red[7];
        float m = s / (float)HWs;
        float var = s2 / (float)HWs - m * m;
        mu[ch] = m;
        rs[ch] = rsqrtf(var + 1e-5f);
    }
}

// ---------------------------------------------------------------------------
// out = x + (d - mu)*rs   (elementwise, NCHW)
// ---------------------------------------------------------------------------
__global__ __launch_bounds__(256) void final_kernel(
    const float* __restrict__ x, float* __restrict__ outp,
    const float* __restrict__ mu, const float* __restrict__ rs) {
    size_t i = ((size_t)blockIdx.x * 256 + threadIdx.x) * 4;
    int ch = (int)(i / HWs);
    float4 xv = *(const float4*)&x[i];
    float4 dv = *(const float4*)&outp[i];
    float m = mu[ch], r = rs[ch];
    float4 ov;
    ov.x = xv.x + (dv.x - m) * r;
    ov.y = xv.y + (dv.y - m) * r;
    ov.z = xv.z + (dv.z - m) * r;
    ov.w = xv.w + (dv.w - m) * r;
    *(float4*)&outp[i] = ov;
}

// ---------------------------------------------------------------------------
extern "C" void kernel_launch(void* const* d_in, const int* in_sizes, int n_in,
                              void* d_out, int out_size, void* d_ws,
                              size_t ws_size, hipStream_t stream) {
    (void)in_sizes; (void)n_in; (void)out_size; (void)ws_size;
    const float* x    = (const float*)d_in[0];
    const float* lo   = (const float*)d_in[1];
    const float* wom1 = (const float*)d_in[2];
    const float* bom1 = (const float*)d_in[3];
    const float* w1   = (const float*)d_in[4];
    const float* b1   = (const float*)d_in[5];
    const float* wom2 = (const float*)d_in[6];
    const float* bom2 = (const float*)d_in[7];
    const float* w2   = (const float*)d_in[8];
    const float* b2   = (const float*)d_in[9];
    float* out = (float*)d_out;

    float* xh   = (float*)d_ws;            // 9437184 (NHWC scratch, reused for r1)
    float* samp = xh + 9437184;            // 5308416
    float* wT1  = samp + 5308416;          // 9*128*28 = 32256
    float* wT2  = wT1 + 32256;
    float* Wt1  = wT2 + 32256;             // 9*128*128 = 147456
    float* Wt2  = Wt1 + 147456;
    float* mu1  = Wt2 + 147456;
    float* rs1  = mu1 + 256;
    float* mu2  = rs1 + 256;
    float* rs2  = mu2 + 256;

    // weight pre-transposes
    transpose_w_kernel<<<(9 * CCH * 28 + 255) / 256, 256, 0, stream>>>(wom1, wT1, 27, 28);
    transpose_w_kernel<<<(9 * CCH * 28 + 255) / 256, 256, 0, stream>>>(wom2, wT2, 27, 28);
    transpose_w_kernel<<<(9 * CCH * 128 + 255) / 256, 256, 0, stream>>>(w1, Wt1, 128, 128);
    transpose_w_kernel<<<(9 * CCH * 128 + 255) / 256, 256, 0, stream>>>(w2, Wt2, 128, 128);

    // x -> NHWC
    transpose_nhwc_kernel<<<9216, 256, 0, stream>>>(x, xh, nullptr, nullptr, 0);

    // ---- block 1 ----
    om_conv_kernel<<<NPIX / 256, 256, 0, stream>>>(lo, wT1, bom1, samp);
    dcn_kernel<<<BB * HH * (WW / DP), 256, 0, stream>>>(xh, samp, Wt1, b1, out);
    stats_kernel<<<256, 256, 0, stream>>>(out, mu1, rs1);
    transpose_nhwc_kernel<<<9216, 256, 0, stream>>>(out, xh, mu1, rs1, 1);  // r1 NHWC

    // ---- block 2 ----
    om_conv_kernel<<<NPIX / 256, 256, 0, stream>>>(lo, wT2, bom2, samp);
    dcn_kernel<<<BB * HH * (WW / DP), 256, 0, stream>>>(xh, samp, Wt2, b2, out);
    stats_kernel<<<256, 256, 0, stream>>>(out, mu2, rs2);

    // residual add (in-place on d_out)
    final_kernel<<<9216, 256, 0, stream>>>(x, out, mu2, rs2);
}

// Round 3
// 1074.413 us; speedup vs baseline: 1.3837x; 1.3837x over previous
//
#include <hip/hip_runtime.h>
#include <hip/hip_bf16.h>
#include <math.h>

#define BB 2
#define CCH 128
#define HH 192
#define WW 192
#define KK 9
#define HWs (HH*WW)          // 36864
#define NPIX (BB*HWs)        // 73728

typedef short bf16x8 __attribute__((ext_vector_type(8)));
typedef float f32x4 __attribute__((ext_vector_type(4)));

__device__ __forceinline__ int iclamp(int v, int lo, int hi) {
    return v < lo ? lo : (v > hi ? hi : v);
}

__device__ __forceinline__ unsigned short f2bf(float f) {
    union { __hip_bfloat16 h; unsigned short u; } cvt;
    cvt.h = __float2bfloat16(f);
    return cvt.u;
}

// ---------------------------------------------------------------------------
// om-weight pre-transpose: (27, C, 3, 3) -> (9, C, 28) fp32 [o<27, pad 0]
// ---------------------------------------------------------------------------
__global__ void transpose_w_kernel(const float* __restrict__ in,
                                   float* __restrict__ outp, int O, int OP) {
    int idx = blockIdx.x * 256 + threadIdx.x;
    int total = 9 * CCH * OP;
    if (idx >= total) return;
    int o = idx % OP;
    int c = (idx / OP) % CCH;
    int tap = idx / (OP * CCH);
    outp[idx] = (o < O) ? in[(o * CCH + c) * 9 + tap] : 0.0f;
}

// ---------------------------------------------------------------------------
// DCN-weight pre-transpose to bf16: (O,C,3,3) -> (9, O, C) bf16
// ---------------------------------------------------------------------------
__global__ void transpose_wb_kernel(const float* __restrict__ in,
                                    unsigned short* __restrict__ outp) {
    int idx = blockIdx.x * 256 + threadIdx.x;   // 9*128*128 = 147456
    if (idx >= 9 * CCH * CCH) return;
    int c = idx % CCH;
    int o = (idx / CCH) % CCH;
    int tap = idx / (CCH * CCH);
    outp[idx] = f2bf(in[(o * CCH + c) * 9 + tap]);
}

// ---------------------------------------------------------------------------
// NCHW -> NHWC transpose with optional instance-norm + relu
// ---------------------------------------------------------------------------
__global__ __launch_bounds__(256) void transpose_nhwc_kernel(
    const float* __restrict__ in, float* __restrict__ outp,
    const float* __restrict__ mu, const float* __restrict__ rs, int do_relu) {
    __shared__ float tile[32][33];
    int blk = blockIdx.x;                 // ((b*H + y)*6 + xt)*4 + ct
    int ct = blk & 3;
    int rest = blk >> 2;
    int xt = rest % 6;
    int rest2 = rest / 6;
    int y = rest2 % HH;
    int b = rest2 / HH;
    int i = threadIdx.x & 31;
    int j = threadIdx.x >> 5;             // 0..7
#pragma unroll
    for (int r = 0; r < 4; ++r) {
        int cl = j + r * 8;
        int c = ct * 32 + cl;
        float v = in[((size_t)(b * CCH + c) * HH + y) * WW + xt * 32 + i];
        if (mu != nullptr) v = (v - mu[b * CCH + c]) * rs[b * CCH + c];
        if (do_relu) v = fmaxf(v, 0.0f);
        tile[cl][i] = v;
    }
    __syncthreads();
#pragma unroll
    for (int r = 0; r < 4; ++r) {
        int xl = j + r * 8;
        outp[(((size_t)b * HH + y) * WW + xt * 32 + xl) * CCH + ct * 32 + i] =
            tile[i][xl];
    }
}

// ---------------------------------------------------------------------------
// Offset/mask conv (27 out ch, 3x3, pad 1) fused with sampling-record gen.
// ---------------------------------------------------------------------------
__global__ __launch_bounds__(256) void om_conv_kernel(
    const float* __restrict__ lo,    // (B,C,H,W)
    const float* __restrict__ wT,    // (9, C, 28) padded
    const float* __restrict__ bom,   // (27)
    float* __restrict__ samp) {      // (B,H,W,9,8)
    int pix = blockIdx.x * 256 + threadIdx.x;   // exactly 73728
    int b = pix / HWs;
    int rem = pix % HWs;
    int y = rem / WW;
    int x = rem % WW;
    float acc[27];
#pragma unroll
    for (int o = 0; o < 27; ++o) acc[o] = bom[o];
    const float* lob = lo + (size_t)b * CCH * HWs;
#pragma unroll
    for (int tap = 0; tap < 9; ++tap) {
        int ty = tap / 3 - 1, tx = tap % 3 - 1;
        int yy = y + ty, xx = x + tx;
        bool ok = (yy >= 0 && yy < HH && xx >= 0 && xx < WW);
        int yyc = iclamp(yy, 0, HH - 1), xxc = iclamp(xx, 0, WW - 1);
        const float* lp = lob + yyc * WW + xxc;
        const float* wp = wT + tap * CCH * 28;
#pragma unroll 2
        for (int c = 0; c < CCH; ++c) {
            float v = lp[(size_t)c * HWs];
            v = ok ? v : 0.0f;
            const float* wpc = wp + c * 28;
#pragma unroll
            for (int o = 0; o < 27; ++o) acc[o] = fmaf(v, wpc[o], acc[o]);
        }
    }
    size_t sbase = (size_t)pix * 72;
#pragma unroll
    for (int k = 0; k < 9; ++k) {
        float dy = acc[2 * k], dx = acc[2 * k + 1];
        float m = 1.0f / (1.0f + __expf(-acc[18 + k]));
        float py = (float)y + (float)(k / 3 - 1) + dy;
        float px = (float)x + (float)(k % 3 - 1) + dx;
        py = fminf(fmaxf(py, -2.0f), (float)(HH + 1));
        px = fminf(fmaxf(px, -2.0f), (float)(WW + 1));
        float y0f = floorf(py), x0f = floorf(px);
        float ay = py - y0f, ax = px - x0f;
        int y0 = (int)y0f, x0 = (int)x0f;
        int y1 = y0 + 1, x1 = x0 + 1;
        bool vy0 = (y0 >= 0 && y0 < HH), vy1 = (y1 >= 0 && y1 < HH);
        bool vx0 = (x0 >= 0 && x0 < WW), vx1 = (x1 >= 0 && x1 < WW);
        int y0c = iclamp(y0, 0, HH - 1), y1c = iclamp(y1, 0, HH - 1);
        int x0c = iclamp(x0, 0, WW - 1), x1c = iclamp(x1, 0, WW - 1);
        float w00 = (1.0f - ay) * (1.0f - ax) * ((vy0 && vx0) ? m : 0.0f);
        float w01 = (1.0f - ay) * ax * ((vy0 && vx1) ? m : 0.0f);
        float w10 = ay * (1.0f - ax) * ((vy1 && vx0) ? m : 0.0f);
        float w11 = ay * ax * ((vy1 && vx1) ? m : 0.0f);
        float4 s0, s1;
        s0.x = __int_as_float(y0c * WW + x0c);
        s0.y = __int_as_float(y0c * WW + x1c);
        s0.z = __int_as_float(y1c * WW + x0c);
        s0.w = __int_as_float(y1c * WW + x1c);
        s1.x = w00; s1.y = w01; s1.z = w10; s1.w = w11;
        *(float4*)(samp + sbase + (size_t)k * 8) = s0;
        *(float4*)(samp + sbase + (size_t)k * 8 + 4) = s1;
    }
}

// ---------------------------------------------------------------------------
// DCN via MFMA. Block = 64 pixels x 128 outputs, 256 threads (4 waves).
// Per tap k: preload W bf16 frags (global->reg), gather S into LDS as bf16
// [p=64][c stride 136], barrier, 32x mfma_f32_16x16x32_bf16 per wave, barrier.
// S_lds row stride 272 B (== 16 mod 128) puts b128 frag reads at the
// 8-access/bank floor; gather ds_write_b32 (packed bf16 pair) conflict-free.
// ---------------------------------------------------------------------------
#define DP 64
#define SSTR 136   // bf16 elems per S row (128 + 8 pad)
__global__ __launch_bounds__(256) void dcn_kernel(
    const float* __restrict__ xh,           // (B,H,W,C) NHWC fp32
    const float* __restrict__ samp,         // (B,H,W,9,8)
    const unsigned short* __restrict__ Wb,  // (9, O, C) bf16
    const float* __restrict__ bias,         // (128)
    float* __restrict__ outp) {             // (B,C,H,W)
    __shared__ unsigned S_lds[DP * (SSTR / 2)];   // 17408 B
    int blk = blockIdx.x;               // 1152
    int xt = blk % (WW / DP);
    int y = (blk / (WW / DP)) % HH;
    int b = blk / ((WW / DP) * HH);
    int x0 = xt * DP;
    int t = threadIdx.x;
    int l = t & 63;           // lane
    int q = l & 15;           // frag row/col index
    int g = l >> 4;           // frag k-group
    int w = t >> 6;           // wave id 0..3
    int ob = w * 32;          // wave's output-channel base (2 o-tiles)

    int c0 = (t & 63) * 2;    // gather: channel pair base (per lane)
    int pq = t >> 6;          // gather: pixel quad (wave-uniform)

    const float* xb = xh + (size_t)b * HWs * CCH;
    const unsigned short* Su = (const unsigned short*)S_lds;
    size_t pixrow = ((size_t)(b * HH + y) * WW + x0);
    const float* srow = samp + pixrow * 72;

    f32x4 acc[2][4];
#pragma unroll
    for (int ot = 0; ot < 2; ++ot)
#pragma unroll
        for (int pt = 0; pt < 4; ++pt) acc[ot][pt] = (f32x4)0.0f;

    for (int k = 0; k < KK; ++k) {
        // ---- preload this tap's A (W) fragments: latency hides under gather
        bf16x8 aw[2][4];
#pragma unroll
        for (int ot = 0; ot < 2; ++ot)
#pragma unroll
            for (int ch = 0; ch < 4; ++ch)
                aw[ot][ch] = *(const bf16x8*)&Wb[((size_t)k * CCH +
                             (ob + ot * 16 + q)) * CCH + ch * 32 + g * 8];

        // ---- gather S for this tap (wave-uniform pixel => scalar rec loads)
        const float* reck = srow + (size_t)k * 8;
#pragma unroll 4
        for (int i = 0; i < 16; ++i) {
            int p = pq * 16 + i;
            const float* rp = reck + (size_t)p * 72;
            float4 rA = *(const float4*)rp;       // corner flat indices
            float4 rB = *(const float4*)(rp + 4); // corner weights (mask folded)
            int i00 = __float_as_int(rA.x);
            int i01 = __float_as_int(rA.y);
            int i10 = __float_as_int(rA.z);
            int i11 = __float_as_int(rA.w);
            float2 v00 = *(const float2*)(xb + (size_t)i00 * CCH + c0);
            float2 v01 = *(const float2*)(xb + (size_t)i01 * CCH + c0);
            float2 v10 = *(const float2*)(xb + (size_t)i10 * CCH + c0);
            float2 v11 = *(const float2*)(xb + (size_t)i11 * CCH + c0);
            float s0 = rB.x * v00.x + rB.y * v01.x + rB.z * v10.x + rB.w * v11.x;
            float s1 = rB.x * v00.y + rB.y * v01.y + rB.z * v10.y + rB.w * v11.y;
            unsigned pk = (unsigned)f2bf(s0) | ((unsigned)f2bf(s1) << 16);
            S_lds[p * (SSTR / 2) + (c0 >> 1)] = pk;
        }
        __syncthreads();

        // ---- MFMA: D[o][p] += W[o][c] * S[c][p], c = 0..127
#pragma unroll
        for (int ch = 0; ch < 4; ++ch) {
            bf16x8 bfr[4];
#pragma unroll
            for (int pt = 0; pt < 4; ++pt)
                bfr[pt] = *(const bf16x8*)&Su[(pt * 16 + q) * SSTR +
                                              ch * 32 + g * 8];
#pragma unroll
            for (int ot = 0; ot < 2; ++ot)
#pragma unroll
                for (int pt = 0; pt < 4; ++pt)
                    acc[ot][pt] = __builtin_amdgcn_mfma_f32_16x16x32_bf16(
                        aw[ot][ch], bfr[pt], acc[ot][pt], 0, 0, 0);
        }
        __syncthreads();   // S reads done before next tap's writes
    }

    // ---- epilogue: C/D map col=lane&15 (=p), row=(lane>>4)*4+r (=o_local)
#pragma unroll
    for (int ot = 0; ot < 2; ++ot) {
#pragma unroll
        for (int r = 0; r < 4; ++r) {
            int oG = ob + ot * 16 + g * 4 + r;
            float bo = bias[oG];
            float* orow = outp + ((size_t)(b * CCH + oG) * HH + y) * WW + x0;
#pragma unroll
            for (int pt = 0; pt < 4; ++pt)
                orow[pt * 16 + q] = acc[ot][pt][r] + bo;
        }
    }
}

// ---------------------------------------------------------------------------
// Per-(b,c) mean / rsqrt(var+eps)
// ---------------------------------------------------------------------------
__global__ __launch_bounds__(256) void stats_kernel(
    const float* __restrict__ d, float* __restrict__ mu,
    float* __restrict__ rs) {
    int ch = blockIdx.x;   // 256
    const float* p = d + (size_t)ch * HWs;
    float s = 0.0f, s2 = 0.0f;
    for (int i = threadIdx.x; i < HWs / 4; i += 256) {
        float4 v = *(const float4*)&p[(size_t)i * 4];
        s += v.x + v.y + v.z + v.w;
        s2 += v.x * v.x + v.y * v.y + v.z * v.z + v.w * v.w;
    }
#pragma unroll
    for (int off = 32; off > 0; off >>= 1) {
        s += __shfl_down(s, off);
        s2 += __shfl_down(s2, off);
    }
    __shared__ float red[8];
    int wid = threadIdx.x >> 6;
    if ((threadIdx.x & 63) == 0) { red[wid] = s; red[4 + wid] = s2; }
    __syncthreads();
    if (threadIdx.x == 0) {
        s = red[0] + red[1] + red[2] + red[3];
        s2 = red[4] + red[5] + red[6] + red[7];
        float m = s / (float)HWs;
        float var = s2 / (float)HWs - m * m;
        mu[ch] = m;
        rs[ch] = rsqrtf(var + 1e-5f);
    }
}

// ---------------------------------------------------------------------------
// out = x + (d - mu)*rs   (elementwise, NCHW)
// ---------------------------------------------------------------------------
__global__ __launch_bounds__(256) void final_kernel(
    const float* __restrict__ x, float* __restrict__ outp,
    const float* __restrict__ mu, const float* __restrict__ rs) {
    size_t i = ((size_t)blockIdx.x * 256 + threadIdx.x) * 4;
    int ch = (int)(i / HWs);
    float4 xv = *(const float4*)&x[i];
    float4 dv = *(const float4*)&outp[i];
    float m = mu[ch], r = rs[ch];
    float4 ov;
    ov.x = xv.x + (dv.x - m) * r;
    ov.y = xv.y + (dv.y - m) * r;
    ov.z = xv.z + (dv.z - m) * r;
    ov.w = xv.w + (dv.w - m) * r;
    *(float4*)&outp[i] = ov;
}

// ---------------------------------------------------------------------------
extern "C" void kernel_launch(void* const* d_in, const int* in_sizes, int n_in,
                              void* d_out, int out_size, void* d_ws,
                              size_t ws_size, hipStream_t stream) {
    (void)in_sizes; (void)n_in; (void)out_size; (void)ws_size;
    const float* x    = (const float*)d_in[0];
    const float* lo   = (const float*)d_in[1];
    const float* wom1 = (const float*)d_in[2];
    const float* bom1 = (const float*)d_in[3];
    const float* w1   = (const float*)d_in[4];
    const float* b1   = (const float*)d_in[5];
    const float* wom2 = (const float*)d_in[6];
    const float* bom2 = (const float*)d_in[7];
    const float* w2   = (const float*)d_in[8];
    const float* b2   = (const float*)d_in[9];
    float* out = (float*)d_out;

    float* xh   = (float*)d_ws;            // 9437184 floats (NHWC scratch)
    float* samp = xh + 9437184;            // 5308416
    float* wT1  = samp + 5308416;          // 9*128*28 = 32256
    float* wT2  = wT1 + 32256;
    unsigned short* Wb1 = (unsigned short*)(wT2 + 32256);  // 147456 u16
    unsigned short* Wb2 = Wb1 + 147456;
    float* mu1  = (float*)(Wb2 + 147456);
    float* rs1  = mu1 + 256;
    float* mu2  = rs1 + 256;
    float* rs2  = mu2 + 256;

    // weight pre-transposes
    transpose_w_kernel<<<(9 * CCH * 28 + 255) / 256, 256, 0, stream>>>(wom1, wT1, 27, 28);
    transpose_w_kernel<<<(9 * CCH * 28 + 255) / 256, 256, 0, stream>>>(wom2, wT2, 27, 28);
    transpose_wb_kernel<<<(9 * CCH * CCH + 255) / 256, 256, 0, stream>>>(w1, Wb1);
    transpose_wb_kernel<<<(9 * CCH * CCH + 255) / 256, 256, 0, stream>>>(w2, Wb2);

    // x -> NHWC
    transpose_nhwc_kernel<<<9216, 256, 0, stream>>>(x, xh, nullptr, nullptr, 0);

    // ---- block 1 ----
    om_conv_kernel<<<NPIX / 256, 256, 0, stream>>>(lo, wT1, bom1, samp);
    dcn_kernel<<<BB * HH * (WW / DP), 256, 0, stream>>>(xh, samp, Wb1, b1, out);
    stats_kernel<<<256, 256, 0, stream>>>(out, mu1, rs1);
    transpose_nhwc_kernel<<<9216, 256, 0, stream>>>(out, xh, mu1, rs1, 1);  // r1 NHWC

    // ---- block 2 ----
    om_conv_kernel<<<NPIX / 256, 256, 0, stream>>>(lo, wT2, bom2, samp);
    dcn_kernel<<<BB * HH * (WW / DP), 256, 0, stream>>>(xh, samp, Wb2, b2, out);
    stats_kernel<<<256, 256, 0, stream>>>(out, mu2, rs2);

    // residual add (in-place on d_out)
    final_kernel<<<9216, 256, 0, stream>>>(x, out, mu2, rs2);
}

// Round 4
// 697.925 us; speedup vs baseline: 2.1301x; 1.5394x over previous
//
#include <hip/hip_runtime.h>
#include <hip/hip_bf16.h>
#include <math.h>

#define BB 2
#define CCH 128
#define HH 192
#define WW 192
#define KK 9
#define HWs (HH*WW)          // 36864
#define NPIX (BB*HWs)        // 73728

typedef short bf16x8 __attribute__((ext_vector_type(8)));
typedef float f32x4 __attribute__((ext_vector_type(4)));

__device__ __forceinline__ int iclamp(int v, int lo, int hi) {
    return v < lo ? lo : (v > hi ? hi : v);
}
__device__ __forceinline__ unsigned short f2bf(float f) {
    union { __hip_bfloat16 h; unsigned short u; } cvt;
    cvt.h = __float2bfloat16(f);
    return cvt.u;
}
__device__ __forceinline__ float bflo(unsigned u) {   // low bf16 -> f32
    return __uint_as_float(u << 16);
}
__device__ __forceinline__ float bfhi(unsigned u) {   // high bf16 -> f32
    return __uint_as_float(u & 0xFFFF0000u);
}
__device__ __forceinline__ unsigned pkbf(float lo, float hi) {
    return (unsigned)f2bf(lo) | ((unsigned)f2bf(hi) << 16);
}

// ---------------------------------------------------------------------------
// DCN-weight pre-transpose to bf16: (O,C,3,3) -> (9, O=128, C=128) bf16
// ---------------------------------------------------------------------------
__global__ void transpose_wb_kernel(const float* __restrict__ in,
                                    unsigned short* __restrict__ outp) {
    int idx = blockIdx.x * 256 + threadIdx.x;   // 9*128*128 = 147456
    if (idx >= 9 * CCH * CCH) return;
    int c = idx % CCH;
    int o = (idx / CCH) % CCH;
    int tap = idx / (CCH * CCH);
    outp[idx] = f2bf(in[(o * CCH + c) * 9 + tap]);
}

// ---------------------------------------------------------------------------
// om-weight pre-transpose to bf16: (27,C,3,3) -> (9, 32, C) bf16, o>=27 -> 0
// ---------------------------------------------------------------------------
__global__ void transpose_womb_kernel(const float* __restrict__ in,
                                      unsigned short* __restrict__ outp) {
    int idx = blockIdx.x * 256 + threadIdx.x;   // 9*32*128 = 36864
    if (idx >= 9 * 32 * CCH) return;
    int c = idx % CCH;
    int o = (idx / CCH) % 32;
    int tap = idx / (CCH * 32);
    outp[idx] = (o < 27) ? f2bf(in[(o * CCH + c) * 9 + tap]) : 0;
}

// ---------------------------------------------------------------------------
// NCHW f32 -> NHWC bf16, optional instance-norm + relu.
// Block = one (b, y, 32-x segment). LDS tile [128][33].
// ---------------------------------------------------------------------------
__global__ __launch_bounds__(256) void to_nhwc_bf16(
    const float* __restrict__ in, unsigned short* __restrict__ outp,
    const float* __restrict__ mu, const float* __restrict__ rs, int do_relu) {
    __shared__ float tile[CCH][33];
    int blk = blockIdx.x;                 // (b*192 + y)*6 + xt
    int xt = blk % 6;
    int y = (blk / 6) % HH;
    int b = blk / (6 * HH);
    int x0 = xt * 32;
    int t = threadIdx.x;
    int xr = (t & 7) * 4;
    int cr = t >> 3;                      // 0..31
#pragma unroll
    for (int it = 0; it < 4; ++it) {
        int c = it * 32 + cr;
        float4 v = *(const float4*)&in[((size_t)(b * CCH + c) * HH + y) * WW + x0 + xr];
        if (mu != nullptr) {
            float m = mu[b * CCH + c], r = rs[b * CCH + c];
            v.x = (v.x - m) * r; v.y = (v.y - m) * r;
            v.z = (v.z - m) * r; v.w = (v.w - m) * r;
        }
        if (do_relu) {
            v.x = fmaxf(v.x, 0.f); v.y = fmaxf(v.y, 0.f);
            v.z = fmaxf(v.z, 0.f); v.w = fmaxf(v.w, 0.f);
        }
        tile[c][xr] = v.x; tile[c][xr + 1] = v.y;
        tile[c][xr + 2] = v.z; tile[c][xr + 3] = v.w;
    }
    __syncthreads();
    int px = t >> 3;                      // 0..31
    int wp = t & 7;                       // 0..7
    size_t wbase = (((size_t)(b * HH + y)) * WW + x0 + px) * (CCH / 2);
    unsigned* outw = (unsigned*)outp;
#pragma unroll
    for (int it = 0; it < 8; ++it) {
        int ch = it * 16 + wp * 2;
        outw[wbase + it * 8 + wp] = pkbf(tile[ch][px], tile[ch + 1][px]);
    }
}

// ---------------------------------------------------------------------------
// Offset/mask conv via MFMA + sampling-record generation.
// Block = 64 px (4 waves x 16 px). Wave: 16 px x 32 out-ch, K = 9*128.
// B-frag loaded directly from NHWC bf16 lo (regular taps); OOB -> zero frag.
// Epilogue: per-wave LDS transpose [16 px][33] then per-lane record math.
// ---------------------------------------------------------------------------
__global__ __launch_bounds__(256) void om_mfma_kernel(
    const unsigned short* __restrict__ lob,   // (B,H,W,C) bf16
    const unsigned short* __restrict__ Wob,   // (9,32,128) bf16
    const float* __restrict__ bom,            // (27)
    float* __restrict__ samp) {               // (B,H,W,9,8)
    __shared__ float s_om[4][16 * 33];
    int blk = blockIdx.x;                 // (b*192+y)*3 + xt  -> 1152
    int xt = blk % 3;
    int y = (blk / 3) % HH;
    int b = blk / (3 * HH);
    int t = threadIdx.x;
    int l = t & 63, q = l & 15, g = l >> 4, w = t >> 6;
    int px = xt * 64 + w * 16 + q;
    int cb = g * 8;
    f32x4 acc0 = (f32x4)0.f, acc1 = (f32x4)0.f;

    for (int k = 0; k < KK; ++k) {
        int ty = k / 3 - 1, tx = k % 3 - 1;
        int yy = y + ty, xx = px + tx;
        bool ok = (yy >= 0 && yy < HH && xx >= 0 && xx < WW);
        int yyc = iclamp(yy, 0, HH - 1), xxc = iclamp(xx, 0, WW - 1);
        const unsigned short* lrow = lob + ((size_t)(b * HH + yyc) * WW + xxc) * CCH;
#pragma unroll
        for (int ch = 0; ch < 4; ++ch) {
            bf16x8 a0 = *(const bf16x8*)&Wob[((size_t)k * 32 + q) * CCH + ch * 32 + cb];
            bf16x8 a1 = *(const bf16x8*)&Wob[((size_t)k * 32 + 16 + q) * CCH + ch * 32 + cb];
            bf16x8 bb = *(const bf16x8*)&lrow[ch * 32 + cb];
            if (!ok) bb = (bf16x8)0;
            acc0 = __builtin_amdgcn_mfma_f32_16x16x32_bf16(a0, bb, acc0, 0, 0, 0);
            acc1 = __builtin_amdgcn_mfma_f32_16x16x32_bf16(a1, bb, acc1, 0, 0, 0);
        }
    }
    // D map: col=lane&15=q (pixel), row=g*4+r (+16 for acc1) = out channel
    float* so = s_om[w];
#pragma unroll
    for (int r = 0; r < 4; ++r) {
        int o0 = g * 4 + r;               // 0..15, always < 27
        so[q * 33 + o0] = acc0[r] + bom[o0];
        int o1 = 16 + g * 4 + r;          // 16..31
        so[q * 33 + o1] = acc1[r] + ((o1 < 27) ? bom[o1] : 0.f);
    }
    __syncthreads();

    size_t pix = ((size_t)(b * HH + y)) * WW + px;
    for (int tt = g; tt < 9; tt += 4) {   // g=0:{0,4,8} g=1:{1,5} g=2:{2,6} g=3:{3,7}
        float dy = so[q * 33 + 2 * tt];
        float dx = so[q * 33 + 2 * tt + 1];
        float ml = so[q * 33 + 18 + tt];
        float m = 1.0f / (1.0f + __expf(-ml));
        float py = (float)y + (float)(tt / 3 - 1) + dy;
        float pxf = (float)px + (float)(tt % 3 - 1) + dx;
        py = fminf(fmaxf(py, -2.0f), (float)(HH + 1));
        pxf = fminf(fmaxf(pxf, -2.0f), (float)(WW + 1));
        float y0f = floorf(py), x0f = floorf(pxf);
        float ay = py - y0f, ax = pxf - x0f;
        int y0 = (int)y0f, x0i = (int)x0f;
        int y1 = y0 + 1, x1 = x0i + 1;
        bool vy0 = (y0 >= 0 && y0 < HH), vy1 = (y1 >= 0 && y1 < HH);
        bool vx0 = (x0i >= 0 && x0i < WW), vx1 = (x1 >= 0 && x1 < WW);
        int y0c = iclamp(y0, 0, HH - 1), y1c = iclamp(y1, 0, HH - 1);
        int x0c = iclamp(x0i, 0, WW - 1), x1c = iclamp(x1, 0, WW - 1);
        float w00 = (1.0f - ay) * (1.0f - ax) * ((vy0 && vx0) ? m : 0.0f);
        float w01 = (1.0f - ay) * ax * ((vy0 && vx1) ? m : 0.0f);
        float w10 = ay * (1.0f - ax) * ((vy1 && vx0) ? m : 0.0f);
        float w11 = ay * ax * ((vy1 && vx1) ? m : 0.0f);
        float4 s0, s1;
        s0.x = __int_as_float(y0c * WW + x0c);
        s0.y = __int_as_float(y0c * WW + x1c);
        s0.z = __int_as_float(y1c * WW + x0c);
        s0.w = __int_as_float(y1c * WW + x1c);
        s1.x = w00; s1.y = w01; s1.z = w10; s1.w = w11;
        *(float4*)(samp + (pix * 9 + tt) * 8) = s0;
        *(float4*)(samp + (pix * 9 + tt) * 8 + 4) = s1;
    }
}

// ---------------------------------------------------------------------------
// DCN via MFMA, no LDS, no barriers. Block = 64 px (4 independent waves).
// Wave: 16 px x 128 out, K = 9 taps x 128 ch. Lane (q,g) gathers its own
// B-fragment (8 ch of pixel q) in registers; A-frags from bf16 W (L1-hot).
// ---------------------------------------------------------------------------
__global__ __launch_bounds__(256) void dcn_kernel(
    const unsigned short* __restrict__ xb,    // (B,H,W,C) bf16
    const float* __restrict__ samp,           // (B,H,W,9,8)
    const unsigned short* __restrict__ Wb,    // (9,128,128) bf16
    const float* __restrict__ bias,           // (128)
    float* __restrict__ outp) {               // (B,C,H,W)
    int blk = blockIdx.x;               // (b*192+y)*3 + xt  -> 1152
    int xt = blk % 3;
    int y = (blk / 3) % HH;
    int b = blk / (3 * HH);
    int t = threadIdx.x;
    int l = t & 63, q = l & 15, g = l >> 4, w = t >> 6;
    int px = xt * 64 + w * 16 + q;
    int cb = g * 8;
    size_t pix = ((size_t)(b * HH + y)) * WW + px;
    const unsigned short* xbb = xb + (size_t)b * HWs * CCH;
    const float* rec = samp + pix * 72;

    f32x4 acc[8];
#pragma unroll
    for (int ot = 0; ot < 8; ++ot) acc[ot] = (f32x4)0.f;

    for (int k = 0; k < KK; ++k) {
        float4 rA = *(const float4*)(rec + (size_t)k * 8);
        float4 rB = *(const float4*)(rec + (size_t)k * 8 + 4);
        int i00 = __float_as_int(rA.x);
        int i01 = __float_as_int(rA.y);
        int i10 = __float_as_int(rA.z);
        int i11 = __float_as_int(rA.w);
        const unsigned short* p00 = xbb + (size_t)i00 * CCH + cb;
        const unsigned short* p01 = xbb + (size_t)i01 * CCH + cb;
        const unsigned short* p10 = xbb + (size_t)i10 * CCH + cb;
        const unsigned short* p11 = xbb + (size_t)i11 * CCH + cb;
#pragma unroll
        for (int ch = 0; ch < 4; ++ch) {
            uint4 c00 = *(const uint4*)(p00 + ch * 32);
            uint4 c01 = *(const uint4*)(p01 + ch * 32);
            uint4 c10 = *(const uint4*)(p10 + ch * 32);
            uint4 c11 = *(const uint4*)(p11 + ch * 32);
            unsigned bbw[4];
            const unsigned* u00 = (const unsigned*)&c00;
            const unsigned* u01 = (const unsigned*)&c01;
            const unsigned* u10 = (const unsigned*)&c10;
            const unsigned* u11 = (const unsigned*)&c11;
#pragma unroll
            for (int d = 0; d < 4; ++d) {
                float slo = rB.x * bflo(u00[d]) + rB.y * bflo(u01[d]) +
                            rB.z * bflo(u10[d]) + rB.w * bflo(u11[d]);
                float shi = rB.x * bfhi(u00[d]) + rB.y * bfhi(u01[d]) +
                            rB.z * bfhi(u10[d]) + rB.w * bfhi(u11[d]);
                bbw[d] = pkbf(slo, shi);
            }
            uint4 bbu = make_uint4(bbw[0], bbw[1], bbw[2], bbw[3]);
            bf16x8 bb = __builtin_bit_cast(bf16x8, bbu);
            const unsigned short* wkc = Wb + (size_t)k * CCH * CCH + ch * 32 + cb;
#pragma unroll
            for (int ot = 0; ot < 8; ++ot) {
                bf16x8 a = *(const bf16x8*)&wkc[(size_t)(ot * 16 + q) * CCH];
                acc[ot] = __builtin_amdgcn_mfma_f32_16x16x32_bf16(a, bb, acc[ot], 0, 0, 0);
            }
        }
    }
    // D map: col=q (pixel), row=g*4+r within 16-row o-tile
#pragma unroll
    for (int ot = 0; ot < 8; ++ot) {
#pragma unroll
        for (int r = 0; r < 4; ++r) {
            int o = ot * 16 + g * 4 + r;
            outp[((size_t)(b * CCH + o) * HH + y) * WW + px] = acc[ot][r] + bias[o];
        }
    }
}

// ---------------------------------------------------------------------------
// Per-(b,c) mean / rsqrt(var+eps)
// ---------------------------------------------------------------------------
__global__ __launch_bounds__(256) void stats_kernel(
    const float* __restrict__ d, float* __restrict__ mu,
    float* __restrict__ rs) {
    int ch = blockIdx.x;   // 256
    const float* p = d + (size_t)ch * HWs;
    float s = 0.0f, s2 = 0.0f;
    for (int i = threadIdx.x; i < HWs / 4; i += 256) {
        float4 v = *(const float4*)&p[(size_t)i * 4];
        s += v.x + v.y + v.z + v.w;
        s2 += v.x * v.x + v.y * v.y + v.z * v.z + v.w * v.w;
    }
#pragma unroll
    for (int off = 32; off > 0; off >>= 1) {
        s += __shfl_down(s, off);
        s2 += __shfl_down(s2, off);
    }
    __shared__ float red[8];
    int wid = threadIdx.x >> 6;
    if ((threadIdx.x & 63) == 0) { red[wid] = s; red[4 + wid] = s2; }
    __syncthreads();
    if (threadIdx.x == 0) {
        s = red[0] + red[1] + red[2] + red[3];
        s2 = red[4] + red[5] + red[6] + red[7];
        float m = s / (float)HWs;
        float var = s2 / (float)HWs - m * m;
        mu[ch] = m;
        rs[ch] = rsqrtf(var + 1e-5f);
    }
}

// ---------------------------------------------------------------------------
// out = x + (d - mu)*rs   (elementwise, NCHW)
// ---------------------------------------------------------------------------
__global__ __launch_bounds__(256) void final_kernel(
    const float* __restrict__ x, float* __restrict__ outp,
    const float* __restrict__ mu, const float* __restrict__ rs) {
    size_t i = ((size_t)blockIdx.x * 256 + threadIdx.x) * 4;
    int ch = (int)(i / HWs);
    float4 xv = *(const float4*)&x[i];
    float4 dv = *(const float4*)&outp[i];
    float m = mu[ch], r = rs[ch];
    float4 ov;
    ov.x = xv.x + (dv.x - m) * r;
    ov.y = xv.y + (dv.y - m) * r;
    ov.z = xv.z + (dv.z - m) * r;
    ov.w = xv.w + (dv.w - m) * r;
    *(float4*)&outp[i] = ov;
}

// ---------------------------------------------------------------------------
extern "C" void kernel_launch(void* const* d_in, const int* in_sizes, int n_in,
                              void* d_out, int out_size, void* d_ws,
                              size_t ws_size, hipStream_t stream) {
    (void)in_sizes; (void)n_in; (void)out_size; (void)ws_size;
    const float* x    = (const float*)d_in[0];
    const float* lo   = (const float*)d_in[1];
    const float* wom1 = (const float*)d_in[2];
    const float* bom1 = (const float*)d_in[3];
    const float* w1   = (const float*)d_in[4];
    const float* b1   = (const float*)d_in[5];
    const float* wom2 = (const float*)d_in[6];
    const float* bom2 = (const float*)d_in[7];
    const float* w2   = (const float*)d_in[8];
    const float* b2   = (const float*)d_in[9];
    float* out = (float*)d_out;

    char* wsb = (char*)d_ws;
    unsigned short* xbf  = (unsigned short*)wsb;                 // 18,874,368 B (x, then r1)
    unsigned short* lobf = (unsigned short*)(wsb + 18874368);    // 18,874,368 B
    float* samp = (float*)(wsb + 2 * 18874368);                  // 21,233,664 B
    char* wp = wsb + 2 * 18874368 + 21233664;
    unsigned short* Wb1   = (unsigned short*)wp;                 // 294,912 B
    unsigned short* Wb2   = (unsigned short*)(wp + 294912);
    unsigned short* Womb1 = (unsigned short*)(wp + 2 * 294912);  // 73,728 B
    unsigned short* Womb2 = (unsigned short*)(wp + 2 * 294912 + 73728);
    float* mu1 = (float*)(wp + 2 * 294912 + 2 * 73728);
    float* rs1 = mu1 + 256;
    float* mu2 = rs1 + 256;
    float* rs2 = mu2 + 256;

    // weight pre-transposes (bf16)
    transpose_wb_kernel<<<576, 256, 0, stream>>>(w1, Wb1);
    transpose_wb_kernel<<<576, 256, 0, stream>>>(w2, Wb2);
    transpose_womb_kernel<<<144, 256, 0, stream>>>(wom1, Womb1);
    transpose_womb_kernel<<<144, 256, 0, stream>>>(wom2, Womb2);

    // x, lo -> NHWC bf16
    to_nhwc_bf16<<<2304, 256, 0, stream>>>(x, xbf, nullptr, nullptr, 0);
    to_nhwc_bf16<<<2304, 256, 0, stream>>>(lo, lobf, nullptr, nullptr, 0);

    // ---- block 1 ----
    om_mfma_kernel<<<1152, 256, 0, stream>>>(lobf, Womb1, bom1, samp);
    dcn_kernel<<<1152, 256, 0, stream>>>(xbf, samp, Wb1, b1, out);
    stats_kernel<<<256, 256, 0, stream>>>(out, mu1, rs1);
    to_nhwc_bf16<<<2304, 256, 0, stream>>>(out, xbf, mu1, rs1, 1);  // r1 (reuses xbf)

    // ---- block 2 ----
    om_mfma_kernel<<<1152, 256, 0, stream>>>(lobf, Womb2, bom2, samp);
    dcn_kernel<<<1152, 256, 0, stream>>>(xbf, samp, Wb2, b2, out);
    stats_kernel<<<256, 256, 0, stream>>>(out, mu2, rs2);

    // residual add (in-place on d_out)
    final_kernel<<<9216, 256, 0, stream>>>(x, out, mu2, rs2);
}

// Round 6
// 687.969 us; speedup vs baseline: 2.1609x; 1.0145x over previous
//
#include <hip/hip_runtime.h>
#include <hip/hip_bf16.h>
#include <math.h>

#define BB 2
#define CCH 128
#define HH 192
#define WW 192
#define KK 9
#define HWs (HH*WW)          // 36864
#define NPIX (BB*HWs)        // 73728

typedef short bf16x8 __attribute__((ext_vector_type(8)));
typedef float f32x4 __attribute__((ext_vector_type(4)));

__device__ __forceinline__ int iclamp(int v, int lo, int hi) {
    return v < lo ? lo : (v > hi ? hi : v);
}
__device__ __forceinline__ unsigned short f2bf(float f) {
    union { __hip_bfloat16 h; unsigned short u; } cvt;
    cvt.h = __float2bfloat16(f);
    return cvt.u;
}
__device__ __forceinline__ float bflo(unsigned u) {   // low bf16 -> f32
    return __uint_as_float(u << 16);
}
__device__ __forceinline__ float bfhi(unsigned u) {   // high bf16 -> f32
    return __uint_as_float(u & 0xFFFF0000u);
}
__device__ __forceinline__ unsigned pkbf(float lo, float hi) {
    return (unsigned)f2bf(lo) | ((unsigned)f2bf(hi) << 16);
}

// ---------------------------------------------------------------------------
// DCN-weight pre-transpose to bf16: (O,C,3,3) -> (9, O=128, C=128) bf16
// ---------------------------------------------------------------------------
__global__ void transpose_wb_kernel(const float* __restrict__ in,
                                    unsigned short* __restrict__ outp) {
    int idx = blockIdx.x * 256 + threadIdx.x;   // 9*128*128 = 147456
    if (idx >= 9 * CCH * CCH) return;
    int c = idx % CCH;
    int o = (idx / CCH) % CCH;
    int tap = idx / (CCH * CCH);
    outp[idx] = f2bf(in[(o * CCH + c) * 9 + tap]);
}

// ---------------------------------------------------------------------------
// om-weight pre-transpose to bf16: (27,C,3,3) -> (9, 32, C) bf16, o>=27 -> 0
// ---------------------------------------------------------------------------
__global__ void transpose_womb_kernel(const float* __restrict__ in,
                                      unsigned short* __restrict__ outp) {
    int idx = blockIdx.x * 256 + threadIdx.x;   // 9*32*128 = 36864
    if (idx >= 9 * 32 * CCH) return;
    int c = idx % CCH;
    int o = (idx / CCH) % 32;
    int tap = idx / (CCH * 32);
    outp[idx] = (o < 27) ? f2bf(in[(o * CCH + c) * 9 + tap]) : 0;
}

// ---------------------------------------------------------------------------
// NCHW f32 -> NHWC bf16, optional instance-norm + relu.
// ---------------------------------------------------------------------------
__global__ __launch_bounds__(256) void to_nhwc_bf16(
    const float* __restrict__ in, unsigned short* __restrict__ outp,
    const float* __restrict__ mu, const float* __restrict__ rs, int do_relu) {
    __shared__ float tile[CCH][33];
    int blk = blockIdx.x;                 // (b*192 + y)*6 + xt
    int xt = blk % 6;
    int y = (blk / 6) % HH;
    int b = blk / (6 * HH);
    int x0 = xt * 32;
    int t = threadIdx.x;
    int xr = (t & 7) * 4;
    int cr = t >> 3;                      // 0..31
#pragma unroll
    for (int it = 0; it < 4; ++it) {
        int c = it * 32 + cr;
        float4 v = *(const float4*)&in[((size_t)(b * CCH + c) * HH + y) * WW + x0 + xr];
        if (mu != nullptr) {
            float m = mu[b * CCH + c], r = rs[b * CCH + c];
            v.x = (v.x - m) * r; v.y = (v.y - m) * r;
            v.z = (v.z - m) * r; v.w = (v.w - m) * r;
        }
        if (do_relu) {
            v.x = fmaxf(v.x, 0.f); v.y = fmaxf(v.y, 0.f);
            v.z = fmaxf(v.z, 0.f); v.w = fmaxf(v.w, 0.f);
        }
        tile[c][xr] = v.x; tile[c][xr + 1] = v.y;
        tile[c][xr + 2] = v.z; tile[c][xr + 3] = v.w;
    }
    __syncthreads();
    int px = t >> 3;                      // 0..31
    int wp = t & 7;                       // 0..7
    size_t wbase = (((size_t)(b * HH + y)) * WW + x0 + px) * (CCH / 2);
    unsigned* outw = (unsigned*)outp;
#pragma unroll
    for (int it = 0; it < 8; ++it) {
        int ch = it * 16 + wp * 2;
        outw[wbase + it * 8 + wp] = pkbf(tile[ch][px], tile[ch + 1][px]);
    }
}

// ---------------------------------------------------------------------------
// Offset/mask conv via MFMA + sampling-record generation.
// XCD swizzle: work-id blk = (bid&7)*144 + bid>>3 (1152 = 8*144, bijective);
// each XCD gets a 48-row band of one batch -> lo band L2-resident.
// samp layout: [blk][k][64 px][8] -> coalesced reads in dcn.
// ---------------------------------------------------------------------------
__global__ __launch_bounds__(256) void om_mfma_kernel(
    const unsigned short* __restrict__ lob,   // (B,H,W,C) bf16
    const unsigned short* __restrict__ Wob,   // (9,32,128) bf16
    const float* __restrict__ bom,            // (27)
    float* __restrict__ samp) {               // (1152,9,64,8)
    __shared__ float s_om[4][16 * 33];
    int bid = blockIdx.x;
    int blk = (bid & 7) * 144 + (bid >> 3);   // XCD band swizzle
    int xt = blk % 3;
    int y = (blk / 3) % HH;
    int b = blk / (3 * HH);
    int t = threadIdx.x;
    int l = t & 63, q = l & 15, g = l >> 4, w = t >> 6;
    int px = xt * 64 + w * 16 + q;
    int cb = g * 8;
    f32x4 acc0 = (f32x4)0.f, acc1 = (f32x4)0.f;

    for (int k = 0; k < KK; ++k) {
        int ty = k / 3 - 1, tx = k % 3 - 1;
        int yy = y + ty, xx = px + tx;
        bool ok = (yy >= 0 && yy < HH && xx >= 0 && xx < WW);
        int yyc = iclamp(yy, 0, HH - 1), xxc = iclamp(xx, 0, WW - 1);
        const unsigned short* lrow = lob + ((size_t)(b * HH + yyc) * WW + xxc) * CCH;
#pragma unroll
        for (int ch = 0; ch < 4; ++ch) {
            bf16x8 a0 = *(const bf16x8*)&Wob[((size_t)k * 32 + q) * CCH + ch * 32 + cb];
            bf16x8 a1 = *(const bf16x8*)&Wob[((size_t)k * 32 + 16 + q) * CCH + ch * 32 + cb];
            bf16x8 bb = *(const bf16x8*)&lrow[ch * 32 + cb];
            if (!ok) bb = (bf16x8)0;
            acc0 = __builtin_amdgcn_mfma_f32_16x16x32_bf16(a0, bb, acc0, 0, 0, 0);
            acc1 = __builtin_amdgcn_mfma_f32_16x16x32_bf16(a1, bb, acc1, 0, 0, 0);
        }
    }
    // D map: col=lane&15=q (pixel), row=g*4+r (+16 for acc1) = out channel
    float* so = s_om[w];
#pragma unroll
    for (int r = 0; r < 4; ++r) {
        int o0 = g * 4 + r;               // 0..15, always < 27
        so[q * 33 + o0] = acc0[r] + bom[o0];
        int o1 = 16 + g * 4 + r;          // 16..31
        so[q * 33 + o1] = acc1[r] + ((o1 < 27) ? bom[o1] : 0.f);
    }
    __syncthreads();

    for (int tt = g; tt < 9; tt += 4) {   // g=0:{0,4,8} g=1:{1,5} g=2:{2,6} g=3:{3,7}
        float dy = so[q * 33 + 2 * tt];
        float dx = so[q * 33 + 2 * tt + 1];
        float ml = so[q * 33 + 18 + tt];
        float m = 1.0f / (1.0f + __expf(-ml));
        float py = (float)y + (float)(tt / 3 - 1) + dy;
        float pxf = (float)px + (float)(tt % 3 - 1) + dx;
        py = fminf(fmaxf(py, -2.0f), (float)(HH + 1));
        pxf = fminf(fmaxf(pxf, -2.0f), (float)(WW + 1));
        float y0f = floorf(py), x0f = floorf(pxf);
        float ay = py - y0f, ax = pxf - x0f;
        int y0 = (int)y0f, x0i = (int)x0f;
        int y1 = y0 + 1, x1 = x0i + 1;
        bool vy0 = (y0 >= 0 && y0 < HH), vy1 = (y1 >= 0 && y1 < HH);
        bool vx0 = (x0i >= 0 && x0i < WW), vx1 = (x1 >= 0 && x1 < WW);
        int y0c = iclamp(y0, 0, HH - 1), y1c = iclamp(y1, 0, HH - 1);
        int x0c = iclamp(x0i, 0, WW - 1), x1c = iclamp(x1, 0, WW - 1);
        float w00 = (1.0f - ay) * (1.0f - ax) * ((vy0 && vx0) ? m : 0.0f);
        float w01 = (1.0f - ay) * ax * ((vy0 && vx1) ? m : 0.0f);
        float w10 = ay * (1.0f - ax) * ((vy1 && vx0) ? m : 0.0f);
        float w11 = ay * ax * ((vy1 && vx1) ? m : 0.0f);
        float4 s0, s1;
        s0.x = __int_as_float(y0c * WW + x0c);
        s0.y = __int_as_float(y0c * WW + x1c);
        s0.z = __int_as_float(y1c * WW + x0c);
        s0.w = __int_as_float(y1c * WW + x1c);
        s1.x = w00; s1.y = w01; s1.z = w10; s1.w = w11;
        float* sp = samp + (((size_t)blk * 9 + tt) * 64 + w * 16 + q) * 8;
        *(float4*)sp = s0;
        *(float4*)(sp + 4) = s1;
    }
}

// ---------------------------------------------------------------------------
// DCN via MFMA, no LDS/barriers. Same XCD band swizzle as om (shared work-id
// space). Wave: 16 px x 128 out. Lane (q,g) gathers its own B-frag; records
// read coalesced from [blk][k][64][8]; k+1 records prefetched.
// ---------------------------------------------------------------------------
__global__ __launch_bounds__(256) void dcn_kernel(
    const unsigned short* __restrict__ xb,    // (B,H,W,C) bf16
    const float* __restrict__ samp,           // (1152,9,64,8)
    const unsigned short* __restrict__ Wb,    // (9,128,128) bf16
    const float* __restrict__ bias,           // (128)
    float* __restrict__ outp) {               // (B,C,H,W)
    int bid = blockIdx.x;
    int blk = (bid & 7) * 144 + (bid >> 3);   // XCD band swizzle
    int xt = blk % 3;
    int y = (blk / 3) % HH;
    int b = blk / (3 * HH);
    int t = threadIdx.x;
    int l = t & 63, q = l & 15, g = l >> 4, w = t >> 6;
    int px = xt * 64 + w * 16 + q;
    int cb = g * 8;
    int p_in = w * 16 + q;
    const unsigned short* xbb = xb + (size_t)b * HWs * CCH;
    const float* rec = samp + (size_t)blk * 9 * 64 * 8;

    f32x4 acc[8];
#pragma unroll
    for (int ot = 0; ot < 8; ++ot) acc[ot] = (f32x4)0.f;

    float4 rA = *(const float4*)(rec + (size_t)p_in * 8);
    float4 rB = *(const float4*)(rec + (size_t)p_in * 8 + 4);
    for (int k = 0; k < KK; ++k) {
        int kn = (k < 8) ? k + 1 : 8;
        float4 nA = *(const float4*)(rec + ((size_t)kn * 64 + p_in) * 8);
        float4 nB = *(const float4*)(rec + ((size_t)kn * 64 + p_in) * 8 + 4);
        int i00 = __float_as_int(rA.x);
        int i01 = __float_as_int(rA.y);
        int i10 = __float_as_int(rA.z);
        int i11 = __float_as_int(rA.w);
        const unsigned short* p00 = xbb + (size_t)i00 * CCH + cb;
        const unsigned short* p01 = xbb + (size_t)i01 * CCH + cb;
        const unsigned short* p10 = xbb + (size_t)i10 * CCH + cb;
        const unsigned short* p11 = xbb + (size_t)i11 * CCH + cb;
#pragma unroll
        for (int ch = 0; ch < 4; ++ch) {
            uint4 c00 = *(const uint4*)(p00 + ch * 32);
            uint4 c01 = *(const uint4*)(p01 + ch * 32);
            uint4 c10 = *(const uint4*)(p10 + ch * 32);
            uint4 c11 = *(const uint4*)(p11 + ch * 32);
            // A-frags issued before the combine VALU (independent of gathers)
            const unsigned short* wkc = Wb + (size_t)k * CCH * CCH + ch * 32 + cb;
            bf16x8 aw[8];
#pragma unroll
            for (int ot = 0; ot < 8; ++ot)
                aw[ot] = *(const bf16x8*)&wkc[(size_t)(ot * 16 + q) * CCH];
            unsigned bbw[4];
            const unsigned* u00 = (const unsigned*)&c00;
            const unsigned* u01 = (const unsigned*)&c01;
            const unsigned* u10 = (const unsigned*)&c10;
            const unsigned* u11 = (const unsigned*)&c11;
#pragma unroll
            for (int d = 0; d < 4; ++d) {
                float slo = rB.x * bflo(u00[d]) + rB.y * bflo(u01[d]) +
                            rB.z * bflo(u10[d]) + rB.w * bflo(u11[d]);
                float shi = rB.x * bfhi(u00[d]) + rB.y * bfhi(u01[d]) +
                            rB.z * bfhi(u10[d]) + rB.w * bfhi(u11[d]);
                bbw[d] = pkbf(slo, shi);
            }
            uint4 bbu = make_uint4(bbw[0], bbw[1], bbw[2], bbw[3]);
            bf16x8 bb = __builtin_bit_cast(bf16x8, bbu);
#pragma unroll
            for (int ot = 0; ot < 8; ++ot)
                acc[ot] = __builtin_amdgcn_mfma_f32_16x16x32_bf16(aw[ot], bb, acc[ot], 0, 0, 0);
        }
        rA = nA; rB = nB;
    }
    // D map: col=q (pixel), row=g*4+r within 16-row o-tile
#pragma unroll
    for (int ot = 0; ot < 8; ++ot) {
#pragma unroll
        for (int r = 0; r < 4; ++r) {
            int o = ot * 16 + g * 4 + r;
            outp[((size_t)(b * CCH + o) * HH + y) * WW + px] = acc[ot][r] + bias[o];
        }
    }
}

// ---------------------------------------------------------------------------
// Per-(b,c) mean / rsqrt(var+eps)
// ---------------------------------------------------------------------------
__global__ __launch_bounds__(256) void stats_kernel(
    const float* __restrict__ d, float* __restrict__ mu,
    float* __restrict__ rs) {
    int ch = blockIdx.x;   // 256
    const float* p = d + (size_t)ch * HWs;
    float s = 0.0f, s2 = 0.0f;
    for (int i = threadIdx.x; i < HWs / 4; i += 256) {
        float4 v = *(const float4*)&p[(size_t)i * 4];
        s += v.x + v.y + v.z + v.w;
        s2 += v.x * v.x + v.y * v.y + v.z * v.z + v.w * v.w;
    }
#pragma unroll
    for (int off = 32; off > 0; off >>= 1) {
        s += __shfl_down(s, off);
        s2 += __shfl_down(s2, off);
    }
    __shared__ float red[8];
    int wid = threadIdx.x >> 6;
    if ((threadIdx.x & 63) == 0) { red[wid] = s; red[4 + wid] = s2; }
    __syncthreads();
    if (threadIdx.x == 0) {
        s = red[0] + red[1] + red[2] + red[3];
        s2 = red[4] + red[5] + red[6] + red[7];
        float m = s / (float)HWs;
        float var = s2 / (float)HWs - m * m;
        mu[ch] = m;
        rs[ch] = rsqrtf(var + 1e-5f);
    }
}

// ---------------------------------------------------------------------------
// out = x + (d - mu)*rs   (elementwise, NCHW)
// ---------------------------------------------------------------------------
__global__ __launch_bounds__(256) void final_kernel(
    const float* __restrict__ x, float* __restrict__ outp,
    const float* __restrict__ mu, const float* __restrict__ rs) {
    size_t i = ((size_t)blockIdx.x * 256 + threadIdx.x) * 4;
    int ch = (int)(i / HWs);
    float4 xv = *(const float4*)&x[i];
    float4 dv = *(const float4*)&outp[i];
    float m = mu[ch], r = rs[ch];
    float4 ov;
    ov.x = xv.x + (dv.x - m) * r;
    ov.y = xv.y + (dv.y - m) * r;
    ov.z = xv.z + (dv.z - m) * r;
    ov.w = xv.w + (dv.w - m) * r;
    *(float4*)&outp[i] = ov;
}

// ---------------------------------------------------------------------------
extern "C" void kernel_launch(void* const* d_in, const int* in_sizes, int n_in,
                              void* d_out, int out_size, void* d_ws,
                              size_t ws_size, hipStream_t stream) {
    (void)in_sizes; (void)n_in; (void)out_size; (void)ws_size;
    const float* x    = (const float*)d_in[0];
    const float* lo   = (const float*)d_in[1];
    const float* wom1 = (const float*)d_in[2];
    const float* bom1 = (const float*)d_in[3];
    const float* w1   = (const float*)d_in[4];
    const float* b1   = (const float*)d_in[5];
    const float* wom2 = (const float*)d_in[6];
    const float* bom2 = (const float*)d_in[7];
    const float* w2   = (const float*)d_in[8];
    const float* b2   = (const float*)d_in[9];
    float* out = (float*)d_out;

    char* wsb = (char*)d_ws;
    unsigned short* xbf  = (unsigned short*)wsb;                 // 18,874,368 B (x, then r1)
    unsigned short* lobf = (unsigned short*)(wsb + 18874368);    // 18,874,368 B
    float* samp = (float*)(wsb + 2 * 18874368);                  // 21,233,664 B
    char* wp = wsb + 2 * 18874368 + 21233664;
    unsigned short* Wb1   = (unsigned short*)wp;                 // 294,912 B
    unsigned short* Wb2   = (unsigned short*)(wp + 294912);
    unsigned short* Womb1 = (unsigned short*)(wp + 2 * 294912);  // 73,728 B
    unsigned short* Womb2 = (unsigned short*)(wp + 2 * 294912 + 73728);
    float* mu1 = (float*)(wp + 2 * 294912 + 2 * 73728);
    float* rs1 = mu1 + 256;
    float* mu2 = rs1 + 256;
    float* rs2 = mu2 + 256;

    // weight pre-transposes (bf16)
    transpose_wb_kernel<<<576, 256, 0, stream>>>(w1, Wb1);
    transpose_wb_kernel<<<576, 256, 0, stream>>>(w2, Wb2);
    transpose_womb_kernel<<<144, 256, 0, stream>>>(wom1, Womb1);
    transpose_womb_kernel<<<144, 256, 0, stream>>>(wom2, Womb2);

    // x, lo -> NHWC bf16
    to_nhwc_bf16<<<2304, 256, 0, stream>>>(x, xbf, nullptr, nullptr, 0);
    to_nhwc_bf16<<<2304, 256, 0, stream>>>(lo, lobf, nullptr, nullptr, 0);

    // ---- block 1 ----
    om_mfma_kernel<<<1152, 256, 0, stream>>>(lobf, Womb1, bom1, samp);
    dcn_kernel<<<1152, 256, 0, stream>>>(xbf, samp, Wb1, b1, out);
    stats_kernel<<<256, 256, 0, stream>>>(out, mu1, rs1);
    to_nhwc_bf16<<<2304, 256, 0, stream>>>(out, xbf, mu1, rs1, 1);  // r1 (reuses xbf)

    // ---- block 2 ----
    om_mfma_kernel<<<1152, 256, 0, stream>>>(lobf, Womb2, bom2, samp);
    dcn_kernel<<<1152, 256, 0, stream>>>(xbf, samp, Wb2, b2, out);
    stats_kernel<<<256, 256, 0, stream>>>(out, mu2, rs2);

    // residual add (in-place on d_out)
    final_kernel<<<9216, 256, 0, stream>>>(x, out, mu2, rs2);
}

// Round 7
// 450.924 us; speedup vs baseline: 3.2968x; 1.5257x over previous
//
#include <hip/hip_runtime.h>
#include <hip/hip_bf16.h>
#include <math.h>

#define BB 2
#define CCH 128
#define HH 192
#define WW 192
#define KK 9
#define HWs (HH*WW)          // 36864
#define NPIX (BB*HWs)        // 73728

typedef short bf16x8 __attribute__((ext_vector_type(8)));
typedef float f32x4 __attribute__((ext_vector_type(4)));

__device__ __forceinline__ int iclamp(int v, int lo, int hi) {
    return v < lo ? lo : (v > hi ? hi : v);
}
__device__ __forceinline__ unsigned short f2bf(float f) {
    union { __hip_bfloat16 h; unsigned short u; } cvt;
    cvt.h = __float2bfloat16(f);
    return cvt.u;
}
__device__ __forceinline__ float bflo(unsigned u) {   // low bf16 -> f32
    return __uint_as_float(u << 16);
}
__device__ __forceinline__ float bfhi(unsigned u) {   // high bf16 -> f32
    return __uint_as_float(u & 0xFFFF0000u);
}
__device__ __forceinline__ unsigned pkbf(float lo, float hi) {
    return (unsigned)f2bf(lo) | ((unsigned)f2bf(hi) << 16);
}

// ---------------------------------------------------------------------------
// DCN-weight pre-transpose to bf16: (O,C,3,3) -> (9, O=128, C=128) bf16
// ---------------------------------------------------------------------------
__global__ void transpose_wb_kernel(const float* __restrict__ in,
                                    unsigned short* __restrict__ outp) {
    int idx = blockIdx.x * 256 + threadIdx.x;   // 9*128*128 = 147456
    if (idx >= 9 * CCH * CCH) return;
    int c = idx % CCH;
    int o = (idx / CCH) % CCH;
    int tap = idx / (CCH * CCH);
    outp[idx] = f2bf(in[(o * CCH + c) * 9 + tap]);
}

// ---------------------------------------------------------------------------
// om-weight pre-transpose to bf16: (27,C,3,3) -> (9, 32, C) bf16, o>=27 -> 0
// ---------------------------------------------------------------------------
__global__ void transpose_womb_kernel(const float* __restrict__ in,
                                      unsigned short* __restrict__ outp) {
    int idx = blockIdx.x * 256 + threadIdx.x;   // 9*32*128 = 36864
    if (idx >= 9 * 32 * CCH) return;
    int c = idx % CCH;
    int o = (idx / CCH) % 32;
    int tap = idx / (CCH * 32);
    outp[idx] = (o < 27) ? f2bf(in[(o * CCH + c) * 9 + tap]) : 0;
}

// ---------------------------------------------------------------------------
// NCHW f32 -> NHWC bf16, optional instance-norm + relu.
// ---------------------------------------------------------------------------
__global__ __launch_bounds__(256) void to_nhwc_bf16(
    const float* __restrict__ in, unsigned short* __restrict__ outp,
    const float* __restrict__ mu, const float* __restrict__ rs, int do_relu) {
    __shared__ float tile[CCH][33];
    int blk = blockIdx.x;                 // (b*192 + y)*6 + xt
    int xt = blk % 6;
    int y = (blk / 6) % HH;
    int b = blk / (6 * HH);
    int x0 = xt * 32;
    int t = threadIdx.x;
    int xr = (t & 7) * 4;
    int cr = t >> 3;                      // 0..31
#pragma unroll
    for (int it = 0; it < 4; ++it) {
        int c = it * 32 + cr;
        float4 v = *(const float4*)&in[((size_t)(b * CCH + c) * HH + y) * WW + x0 + xr];
        if (mu != nullptr) {
            float m = mu[b * CCH + c], r = rs[b * CCH + c];
            v.x = (v.x - m) * r; v.y = (v.y - m) * r;
            v.z = (v.z - m) * r; v.w = (v.w - m) * r;
        }
        if (do_relu) {
            v.x = fmaxf(v.x, 0.f); v.y = fmaxf(v.y, 0.f);
            v.z = fmaxf(v.z, 0.f); v.w = fmaxf(v.w, 0.f);
        }
        tile[c][xr] = v.x; tile[c][xr + 1] = v.y;
        tile[c][xr + 2] = v.z; tile[c][xr + 3] = v.w;
    }
    __syncthreads();
    int px = t >> 3;                      // 0..31
    int wp = t & 7;                       // 0..7
    size_t wbase = (((size_t)(b * HH + y)) * WW + x0 + px) * (CCH / 2);
    unsigned* outw = (unsigned*)outp;
#pragma unroll
    for (int it = 0; it < 8; ++it) {
        int ch = it * 16 + wp * 2;
        outw[wbase + it * 8 + wp] = pkbf(tile[ch][px], tile[ch + 1][px]);
    }
}

// ---------------------------------------------------------------------------
// Offset/mask conv via MFMA + sampling-record generation (unchanged r6).
// ---------------------------------------------------------------------------
__global__ __launch_bounds__(256) void om_mfma_kernel(
    const unsigned short* __restrict__ lob,   // (B,H,W,C) bf16
    const unsigned short* __restrict__ Wob,   // (9,32,128) bf16
    const float* __restrict__ bom,            // (27)
    float* __restrict__ samp) {               // (1152,9,64,8)
    __shared__ float s_om[4][16 * 33];
    int bid = blockIdx.x;
    int blk = (bid & 7) * 144 + (bid >> 3);   // XCD band swizzle
    int xt = blk % 3;
    int y = (blk / 3) % HH;
    int b = blk / (3 * HH);
    int t = threadIdx.x;
    int l = t & 63, q = l & 15, g = l >> 4, w = t >> 6;
    int px = xt * 64 + w * 16 + q;
    int cb = g * 8;
    f32x4 acc0 = (f32x4)0.f, acc1 = (f32x4)0.f;

    for (int k = 0; k < KK; ++k) {
        int ty = k / 3 - 1, tx = k % 3 - 1;
        int yy = y + ty, xx = px + tx;
        bool ok = (yy >= 0 && yy < HH && xx >= 0 && xx < WW);
        int yyc = iclamp(yy, 0, HH - 1), xxc = iclamp(xx, 0, WW - 1);
        const unsigned short* lrow = lob + ((size_t)(b * HH + yyc) * WW + xxc) * CCH;
#pragma unroll
        for (int ch = 0; ch < 4; ++ch) {
            bf16x8 a0 = *(const bf16x8*)&Wob[((size_t)k * 32 + q) * CCH + ch * 32 + cb];
            bf16x8 a1 = *(const bf16x8*)&Wob[((size_t)k * 32 + 16 + q) * CCH + ch * 32 + cb];
            bf16x8 bb = *(const bf16x8*)&lrow[ch * 32 + cb];
            if (!ok) bb = (bf16x8)0;
            acc0 = __builtin_amdgcn_mfma_f32_16x16x32_bf16(a0, bb, acc0, 0, 0, 0);
            acc1 = __builtin_amdgcn_mfma_f32_16x16x32_bf16(a1, bb, acc1, 0, 0, 0);
        }
    }
    // D map: col=lane&15=q (pixel), row=g*4+r (+16 for acc1) = out channel
    float* so = s_om[w];
#pragma unroll
    for (int r = 0; r < 4; ++r) {
        int o0 = g * 4 + r;               // 0..15, always < 27
        so[q * 33 + o0] = acc0[r] + bom[o0];
        int o1 = 16 + g * 4 + r;          // 16..31
        so[q * 33 + o1] = acc1[r] + ((o1 < 27) ? bom[o1] : 0.f);
    }
    __syncthreads();

    for (int tt = g; tt < 9; tt += 4) {   // g=0:{0,4,8} g=1:{1,5} g=2:{2,6} g=3:{3,7}
        float dy = so[q * 33 + 2 * tt];
        float dx = so[q * 33 + 2 * tt + 1];
        float ml = so[q * 33 + 18 + tt];
        float m = 1.0f / (1.0f + __expf(-ml));
        float py = (float)y + (float)(tt / 3 - 1) + dy;
        float pxf = (float)px + (float)(tt % 3 - 1) + dx;
        py = fminf(fmaxf(py, -2.0f), (float)(HH + 1));
        pxf = fminf(fmaxf(pxf, -2.0f), (float)(WW + 1));
        float y0f = floorf(py), x0f = floorf(pxf);
        float ay = py - y0f, ax = pxf - x0f;
        int y0 = (int)y0f, x0i = (int)x0f;
        int y1 = y0 + 1, x1 = x0i + 1;
        bool vy0 = (y0 >= 0 && y0 < HH), vy1 = (y1 >= 0 && y1 < HH);
        bool vx0 = (x0i >= 0 && x0i < WW), vx1 = (x1 >= 0 && x1 < WW);
        int y0c = iclamp(y0, 0, HH - 1), y1c = iclamp(y1, 0, HH - 1);
        int x0c = iclamp(x0i, 0, WW - 1), x1c = iclamp(x1, 0, WW - 1);
        float w00 = (1.0f - ay) * (1.0f - ax) * ((vy0 && vx0) ? m : 0.0f);
        float w01 = (1.0f - ay) * ax * ((vy0 && vx1) ? m : 0.0f);
        float w10 = ay * (1.0f - ax) * ((vy1 && vx0) ? m : 0.0f);
        float w11 = ay * ax * ((vy1 && vx1) ? m : 0.0f);
        float4 s0, s1;
        s0.x = __int_as_float(y0c * WW + x0c);
        s0.y = __int_as_float(y0c * WW + x1c);
        s0.z = __int_as_float(y1c * WW + x0c);
        s0.w = __int_as_float(y1c * WW + x1c);
        s1.x = w00; s1.y = w01; s1.z = w10; s1.w = w11;
        float* sp = samp + (((size_t)blk * 9 + tt) * 64 + w * 16 + q) * 8;
        *(float4*)sp = s0;
        *(float4*)(sp + 4) = s1;
    }
}

// ---------------------------------------------------------------------------
// DCN via MFMA, weights LDS-staged per tap. Block = 64 px, 4 waves.
// Per tap: coalesced-load W_k (32KB) -> XOR-swizzled LDS [row 256B,
// byte ^= ((row&7)<<4)], gather 4 B-frags into regs (both load streams in
// flight together), barrier, 32 ds_read_b128 + 32 MFMA per wave, barrier.
// Cuts per-wave global-load instrs 432 -> 144 (gathers only).
// ---------------------------------------------------------------------------
__global__ __launch_bounds__(256) void dcn_kernel(
    const unsigned short* __restrict__ xb,    // (B,H,W,C) bf16
    const float* __restrict__ samp,           // (1152,9,64,8)
    const unsigned short* __restrict__ Wb,    // (9,128,128) bf16
    const float* __restrict__ bias,           // (128)
    float* __restrict__ outp) {               // (B,C,H,W)
    __shared__ unsigned short s_w[CCH * CCH]; // 32 KB, swizzled rows
    int bid = blockIdx.x;
    int blk = (bid & 7) * 144 + (bid >> 3);   // XCD band swizzle
    int xt = blk % 3;
    int y = (blk / 3) % HH;
    int b = blk / (3 * HH);
    int t = threadIdx.x;
    int l = t & 63, q = l & 15, g = l >> 4, w = t >> 6;
    int px = xt * 64 + w * 16 + q;
    int cb = g * 8;
    int p_in = w * 16 + q;
    const unsigned short* xbb = xb + (size_t)b * HWs * CCH;
    const float* rec = samp + (size_t)blk * 9 * 64 * 8;
    char* swb = (char*)s_w;
    int swz_t = ((t >> 4) & 7) << 4;          // stage swizzle (const per thread)
    int xorq = (q & 7) << 4;                  // read swizzle

    f32x4 acc[8];
#pragma unroll
    for (int ot = 0; ot < 8; ++ot) acc[ot] = (f32x4)0.f;

    float4 rA = *(const float4*)(rec + (size_t)p_in * 8);
    float4 rB = *(const float4*)(rec + (size_t)p_in * 8 + 4);
    for (int k = 0; k < KK; ++k) {
        // ---- stage W_k -> LDS (coalesced reads, swizzled ds_write_b128) ----
        const char* wk = (const char*)(Wb + (size_t)k * CCH * CCH);
#pragma unroll
        for (int j = 0; j < 8; ++j) {
            int off = j * 4096 + t * 16;
            uint4 v = *(const uint4*)(wk + off);
            *(uint4*)(swb + (off ^ swz_t)) = v;
        }
        // ---- record prefetch for k+1 ----
        int kn = (k < 8) ? k + 1 : 8;
        float4 nA = *(const float4*)(rec + ((size_t)kn * 64 + p_in) * 8);
        float4 nB = *(const float4*)(rec + ((size_t)kn * 64 + p_in) * 8 + 4);
        // ---- gather B-fragments for this tap (regs) ----
        int i00 = __float_as_int(rA.x);
        int i01 = __float_as_int(rA.y);
        int i10 = __float_as_int(rA.z);
        int i11 = __float_as_int(rA.w);
        const unsigned short* p00 = xbb + (size_t)i00 * CCH + cb;
        const unsigned short* p01 = xbb + (size_t)i01 * CCH + cb;
        const unsigned short* p10 = xbb + (size_t)i10 * CCH + cb;
        const unsigned short* p11 = xbb + (size_t)i11 * CCH + cb;
        bf16x8 bbv[4];
#pragma unroll
        for (int ch = 0; ch < 4; ++ch) {
            uint4 c00 = *(const uint4*)(p00 + ch * 32);
            uint4 c01 = *(const uint4*)(p01 + ch * 32);
            uint4 c10 = *(const uint4*)(p10 + ch * 32);
            uint4 c11 = *(const uint4*)(p11 + ch * 32);
            unsigned bbw[4];
            const unsigned* u00 = (const unsigned*)&c00;
            const unsigned* u01 = (const unsigned*)&c01;
            const unsigned* u10 = (const unsigned*)&c10;
            const unsigned* u11 = (const unsigned*)&c11;
#pragma unroll
            for (int d = 0; d < 4; ++d) {
                float slo = rB.x * bflo(u00[d]) + rB.y * bflo(u01[d]) +
                            rB.z * bflo(u10[d]) + rB.w * bflo(u11[d]);
                float shi = rB.x * bfhi(u00[d]) + rB.y * bfhi(u01[d]) +
                            rB.z * bfhi(u10[d]) + rB.w * bfhi(u11[d]);
                bbw[d] = pkbf(slo, shi);
            }
            uint4 bbu = make_uint4(bbw[0], bbw[1], bbw[2], bbw[3]);
            bbv[ch] = __builtin_bit_cast(bf16x8, bbu);
        }
        __syncthreads();
        // ---- MFMA from LDS A-frags ----
#pragma unroll
        for (int ch = 0; ch < 4; ++ch) {
            int inner = (ch * 64 + g * 16) ^ xorq;
#pragma unroll
            for (int ot = 0; ot < 8; ++ot) {
                bf16x8 a = *(const bf16x8*)(swb + (ot * 4096 + q * 256 + inner));
                acc[ot] = __builtin_amdgcn_mfma_f32_16x16x32_bf16(a, bbv[ch], acc[ot], 0, 0, 0);
            }
        }
        __syncthreads();   // LDS reads done before next tap's staging writes
        rA = nA; rB = nB;
    }
    // D map: col=q (pixel), row=g*4+r within 16-row o-tile
#pragma unroll
    for (int ot = 0; ot < 8; ++ot) {
#pragma unroll
        for (int r = 0; r < 4; ++r) {
            int o = ot * 16 + g * 4 + r;
            outp[((size_t)(b * CCH + o) * HH + y) * WW + px] = acc[ot][r] + bias[o];
        }
    }
}

// ---------------------------------------------------------------------------
// Per-(b,c) mean / rsqrt(var+eps)
// ---------------------------------------------------------------------------
__global__ __launch_bounds__(256) void stats_kernel(
    const float* __restrict__ d, float* __restrict__ mu,
    float* __restrict__ rs) {
    int ch = blockIdx.x;   // 256
    const float* p = d + (size_t)ch * HWs;
    float s = 0.0f, s2 = 0.0f;
    for (int i = threadIdx.x; i < HWs / 4; i += 256) {
        float4 v = *(const float4*)&p[(size_t)i * 4];
        s += v.x + v.y + v.z + v.w;
        s2 += v.x * v.x + v.y * v.y + v.z * v.z + v.w * v.w;
    }
#pragma unroll
    for (int off = 32; off > 0; off >>= 1) {
        s += __shfl_down(s, off);
        s2 += __shfl_down(s2, off);
    }
    __shared__ float red[8];
    int wid = threadIdx.x >> 6;
    if ((threadIdx.x & 63) == 0) { red[wid] = s; red[4 + wid] = s2; }
    __syncthreads();
    if (threadIdx.x == 0) {
        s = red[0] + red[1] + red[2] + red[3];
        s2 = red[4] + red[5] + red[6] + red[7];
        float m = s / (float)HWs;
        float var = s2 / (float)HWs - m * m;
        mu[ch] = m;
        rs[ch] = rsqrtf(var + 1e-5f);
    }
}

// ---------------------------------------------------------------------------
// out = x + (d - mu)*rs   (elementwise, NCHW)
// ---------------------------------------------------------------------------
__global__ __launch_bounds__(256) void final_kernel(
    const float* __restrict__ x, float* __restrict__ outp,
    const float* __restrict__ mu, const float* __restrict__ rs) {
    size_t i = ((size_t)blockIdx.x * 256 + threadIdx.x) * 4;
    int ch = (int)(i / HWs);
    float4 xv = *(const float4*)&x[i];
    float4 dv = *(const float4*)&outp[i];
    float m = mu[ch], r = rs[ch];
    float4 ov;
    ov.x = xv.x + (dv.x - m) * r;
    ov.y = xv.y + (dv.y - m) * r;
    ov.z = xv.z + (dv.z - m) * r;
    ov.w = xv.w + (dv.w - m) * r;
    *(float4*)&outp[i] = ov;
}

// ---------------------------------------------------------------------------
extern "C" void kernel_launch(void* const* d_in, const int* in_sizes, int n_in,
                              void* d_out, int out_size, void* d_ws,
                              size_t ws_size, hipStream_t stream) {
    (void)in_sizes; (void)n_in; (void)out_size; (void)ws_size;
    const float* x    = (const float*)d_in[0];
    const float* lo   = (const float*)d_in[1];
    const float* wom1 = (const float*)d_in[2];
    const float* bom1 = (const float*)d_in[3];
    const float* w1   = (const float*)d_in[4];
    const float* b1   = (const float*)d_in[5];
    const float* wom2 = (const float*)d_in[6];
    const float* bom2 = (const float*)d_in[7];
    const float* w2   = (const float*)d_in[8];
    const float* b2   = (const float*)d_in[9];
    float* out = (float*)d_out;

    char* wsb = (char*)d_ws;
    unsigned short* xbf  = (unsigned short*)wsb;                 // 18,874,368 B (x, then r1)
    unsigned short* lobf = (unsigned short*)(wsb + 18874368);    // 18,874,368 B
    float* samp = (float*)(wsb + 2 * 18874368);                  // 21,233,664 B
    char* wp = wsb + 2 * 18874368 + 21233664;
    unsigned short* Wb1   = (unsigned short*)wp;                 // 294,912 B
    unsigned short* Wb2   = (unsigned short*)(wp + 294912);
    unsigned short* Womb1 = (unsigned short*)(wp + 2 * 294912);  // 73,728 B
    unsigned short* Womb2 = (unsigned short*)(wp + 2 * 294912 + 73728);
    float* mu1 = (float*)(wp + 2 * 294912 + 2 * 73728);
    float* rs1 = mu1 + 256;
    float* mu2 = rs1 + 256;
    float* rs2 = mu2 + 256;

    // weight pre-transposes (bf16)
    transpose_wb_kernel<<<576, 256, 0, stream>>>(w1, Wb1);
    transpose_wb_kernel<<<576, 256, 0, stream>>>(w2, Wb2);
    transpose_womb_kernel<<<144, 256, 0, stream>>>(wom1, Womb1);
    transpose_womb_kernel<<<144, 256, 0, stream>>>(wom2, Womb2);

    // x, lo -> NHWC bf16
    to_nhwc_bf16<<<2304, 256, 0, stream>>>(x, xbf, nullptr, nullptr, 0);
    to_nhwc_bf16<<<2304, 256, 0, stream>>>(lo, lobf, nullptr, nullptr, 0);

    // ---- block 1 ----
    om_mfma_kernel<<<1152, 256, 0, stream>>>(lobf, Womb1, bom1, samp);
    dcn_kernel<<<1152, 256, 0, stream>>>(xbf, samp, Wb1, b1, out);
    stats_kernel<<<256, 256, 0, stream>>>(out, mu1, rs1);
    to_nhwc_bf16<<<2304, 256, 0, stream>>>(out, xbf, mu1, rs1, 1);  // r1 (reuses xbf)

    // ---- block 2 ----
    om_mfma_kernel<<<1152, 256, 0, stream>>>(lobf, Womb2, bom2, samp);
    dcn_kernel<<<1152, 256, 0, stream>>>(xbf, samp, Wb2, b2, out);
    stats_kernel<<<256, 256, 0, stream>>>(out, mu2, rs2);

    // residual add (in-place on d_out)
    final_kernel<<<9216, 256, 0, stream>>>(x, out, mu2, rs2);
}